// Round 7
// baseline (338.554 us; speedup 1.0000x reference)
//
#include <hip/hip_runtime.h>
#include <cstddef>

#define BB 16
#define LMM 1024
#define LTT 512
#define LL 1536
#define DMODEL 512
#define DINNER 1024
#define NH 16
#define DIPROJ 2192
#define DFF2 2048

typedef __bf16 bf16_t;
typedef bf16_t bf16x2 __attribute__((ext_vector_type(2)));
typedef bf16_t bf16x4 __attribute__((ext_vector_type(4)));
typedef bf16_t bf16x8 __attribute__((ext_vector_type(8)));
typedef float f32x4 __attribute__((ext_vector_type(4)));

typedef __attribute__((address_space(3))) void lds_void;
typedef const __attribute__((address_space(1))) void glb_void;

__device__ __forceinline__ void gload16(const void* g, void* l) {
  __builtin_amdgcn_global_load_lds((glb_void*)g, (lds_void*)l, 16, 0, 0);
}

__device__ inline float block_sum(float v, float* sbuf) {
#pragma unroll
  for (int off = 32; off > 0; off >>= 1) v += __shfl_xor(v, off, 64);
  int w = threadIdx.x >> 6;
  if ((threadIdx.x & 63) == 0) sbuf[w] = v;
  __syncthreads();
  return sbuf[0] + sbuf[1] + sbuf[2] + sbuf[3];
}

__global__ __launch_bounds__(256)
void cvt_w(const float* __restrict__ src, bf16_t* __restrict__ dst, int n)
{
  int i = (blockIdx.x * 256 + threadIdx.x) * 4;
  if (i < n) {
    float4 v = *(const float4*)&src[i];
    bf16x4 o;
    o[0] = (bf16_t)v.x; o[1] = (bf16_t)v.y; o[2] = (bf16_t)v.z; o[3] = (bf16_t)v.w;
    *(bf16x4*)&dst[i] = o;
  }
}

__global__ __launch_bounds__(256)
void prep_u(const float* __restrict__ tgt, const float* __restrict__ memory,
            const float* __restrict__ mem_mask, const float* __restrict__ tgt_mask,
            bf16_t* __restrict__ u, float* __restrict__ tgtm)
{
  __shared__ float sbuf[4];
  const int row = blockIdx.x;              // b*LL + t
  const int b = row / LL;
  const int t = row - b * LL;
  const int tid = threadIdx.x;
  if (t < LMM) {
    float m = mem_mask[b * LMM + t];
    float s = m * m;
    const float* src = memory + ((size_t)b * LMM + t) * DMODEL;
    float2 v = *(const float2*)&src[tid * 2];
    bf16x2 o; o[0] = (bf16_t)(v.x * s); o[1] = (bf16_t)(v.y * s);
    *(bf16x2*)&u[(size_t)row * DMODEL + tid * 2] = o;
  } else {
    const int tt = t - LMM;
    float mk = tgt_mask[b * LTT + tt];
    const float* src = tgt + ((size_t)b * LTT + tt) * DMODEL;
    float2 v = *(const float2*)&src[tid * 2];
    v.x *= mk; v.y *= mk;
    *(float2*)&tgtm[((size_t)b * LTT + tt) * DMODEL + tid * 2] = v;
    float ss = block_sum(v.x * v.x + v.y * v.y, sbuf);
    float inv = rsqrtf(ss * (1.0f / 512.0f) + 1e-6f) * mk;
    bf16x2 o; o[0] = (bf16_t)(v.x * inv); o[1] = (bf16_t)(v.y * inv);
    *(bf16x2*)&u[(size_t)row * DMODEL + tid * 2] = o;
  }
}

// C = A[M,K](bf16) @ W[N,K]^T(bf16), BK=64, 2-phase double-buffered global_load_lds,
// XOR-swizzled LDS, XCD-aware block swizzle.
template<int EPI>
__global__ __launch_bounds__(256)
void gemm_abf(const bf16_t* __restrict__ A, const bf16_t* __restrict__ W,
              int M, int N, int K,
              float* __restrict__ Cf, bf16_t* __restrict__ Cb,
              const float* __restrict__ bias, const float* __restrict__ res,
              bf16_t* __restrict__ zbuf, bf16_t* __restrict__ xbc,
              float* __restrict__ dts, float* __restrict__ labuf,
              const float* __restrict__ dt_bias, const float* __restrict__ A_log)
{
  // XCD-aware bijective swizzle (all grids have nwg % 8 == 0)
  const int nbx = gridDim.x;
  const int nwg = nbx * gridDim.y;
  int flat = blockIdx.y * nbx + blockIdx.x;
  int swz = (flat & 7) * (nwg >> 3) + (flat >> 3);
  const int m0 = (swz / nbx) * 128;
  const int n0 = (swz % nbx) * 128;
  int bq = 0, tbase = 0;
  if (EPI == 4) {
    bq = m0 / LL; tbase = m0 - bq * LL;
    if (n0 + 128 <= DINNER && tbase < LMM) return;
  }
  __shared__ __align__(16) bf16_t As[2][128 * 64];
  __shared__ __align__(16) bf16_t Bs[2][128 * 64];
  const int tid = threadIdx.x;
  const int lane = tid & 63;
  const int wid = tid >> 6;
  const int wr = (wid >> 1) * 64, wc = (wid & 1) * 64;
  const int r = lane & 15;
  const int g = lane >> 4;
  const int r7 = r & 7;
  const int lrow = lane >> 3;
  const int sslot = (lane & 7) ^ lrow;

  int arow[4], brow[4];
#pragma unroll
  for (int ci = 0; ci < 4; ++ci) {
    int tr = wid * 32 + ci * 8 + lrow;
    arow[ci] = m0 + tr;
    int bn = n0 + tr;
    brow[ci] = bn < N ? bn : N - 1;
  }

  auto stage = [&](int buf, int kt) {
#pragma unroll
    for (int ci = 0; ci < 4; ++ci) {
      int chunk = wid * 4 + ci;
      gload16(A + (size_t)arow[ci] * K + kt + sslot * 8, &As[buf][chunk * 512]);
      gload16(W + (size_t)brow[ci] * K + kt + sslot * 8, &Bs[buf][chunk * 512]);
    }
  };

  f32x4 acc[4][4];
#pragma unroll
  for (int m = 0; m < 4; ++m)
#pragma unroll
    for (int n = 0; n < 4; ++n) acc[m][n] = (f32x4){0.f, 0.f, 0.f, 0.f};

  const int NK = K >> 6;
  stage(0, 0);
  __syncthreads();
  for (int ki = 0; ki < NK; ++ki) {
    const int cur = ki & 1;
    if (ki + 1 < NK) stage(cur ^ 1, (ki + 1) << 6);   // prefetch flies under MFMA
#pragma unroll
    for (int c = 0; c < 2; ++c) {
      bf16x8 af[4], bfr[4];
#pragma unroll
      for (int m = 0; m < 4; ++m) {
        int row = wr + m * 16 + r;
        af[m] = *(const bf16x8*)&As[cur][row * 64 + (((c * 4 + g) ^ r7) * 8)];
      }
#pragma unroll
      for (int n = 0; n < 4; ++n) {
        int row = wc + n * 16 + r;
        bfr[n] = *(const bf16x8*)&Bs[cur][row * 64 + (((c * 4 + g) ^ r7) * 8)];
      }
#pragma unroll
      for (int m = 0; m < 4; ++m)
#pragma unroll
        for (int n = 0; n < 4; ++n)
          acc[m][n] = __builtin_amdgcn_mfma_f32_16x16x32_bf16(af[m], bfr[n], acc[m][n], 0, 0, 0);
    }
    if (ki + 1 < NK) __syncthreads();   // drains prefetch (vmcnt 0) + frees cur buffer
  }

#pragma unroll
  for (int m = 0; m < 4; ++m) {
#pragma unroll
    for (int n = 0; n < 4; ++n) {
      int gcol = n0 + wc + n * 16 + r;
      if (gcol >= N) continue;
#pragma unroll
      for (int j = 0; j < 4; ++j) {
        float v = acc[m][n][j];
        if (EPI == 4) {
          int t = tbase + wr + m * 16 + g * 4 + j;
          if (gcol < DINNER) {
            zbuf[(((size_t)(bq * LTT + t - LMM)) << 10) + gcol] = (bf16_t)v;
          } else if (gcol < DINNER + 1152) {
            xbc[(size_t)(bq * LL + t) * 1152 + (gcol - DINNER)] = (bf16_t)v;
          } else {
            int h = gcol - 2176;
            float raw = v + dt_bias[h];
            float d = raw > 20.f ? raw : log1pf(expf(raw));
            size_t ix = (size_t)(bq * LL + t) * 16 + h;
            dts[ix] = d;
            labuf[ix] = -expf(A_log[h]) * d;      // log a
          }
        } else {
          int grow = m0 + wr + m * 16 + g * 4 + j;
          if (EPI == 1) {
            v += bias[gcol];
            v = 0.5f * v * (1.f + erff(v * 0.70710678f));
            Cb[(size_t)grow * N + gcol] = (bf16_t)v;
          } else if (EPI == 2) {
            v += bias[gcol] + res[(size_t)grow * N + gcol];
            Cf[(size_t)grow * N + gcol] = v;
          } else {
            v += res[(size_t)grow * N + gcol];
            Cf[(size_t)grow * N + gcol] = v;
          }
        }
      }
    }
  }
}

// Per (chunk, b): conv+silu B/C (shared across heads); write BtG [b][c][n][t^] (bf16),
// and for c>=8: CcG [b][c-8][t][n^] and S = C@B^T (triangular) in G-layout.
__global__ __launch_bounds__(256)
void sbc_k(const bf16_t* __restrict__ xbc, const float* __restrict__ cw,
           const float* __restrict__ cb, bf16_t* __restrict__ BtG,
           bf16_t* __restrict__ Sg, bf16_t* __restrict__ CcG)
{
  __shared__ __align__(16) bf16_t rawBC[132 * 128];   // rows t0-3..t0+128, 128 ch (B|C)
  __shared__ __align__(16) bf16_t CB[128 * 128];      // conv'd, slot-swizzled rows
  __shared__ float wls[128 * 4];
  __shared__ float bls[128];
  const int c = blockIdx.x, b = blockIdx.y;
  const int t0 = c * 128;
  const int tid = threadIdx.x, lane = tid & 63, wid = tid >> 6;
  const int r = lane & 15, g = lane >> 4;

  if (tid < 128) {
    int gch = 1024 + tid;
#pragma unroll
    for (int k = 0; k < 4; ++k) wls[tid * 4 + k] = cw[gch * 4 + k];
    bls[tid] = cb[gch];
  }
#pragma unroll
  for (int ci = 0; ci < 9; ++ci) {
    int chunk = ci * 4 + wid;
    if (chunk < 33) {
      int F = chunk * 1024 + lane * 16;
      int row = F >> 8, off = F & 255;
      gload16(xbc + (size_t)(b * LL + t0 - 3 + row) * 1152 + 1024 + off / 2,
              &rawBC[chunk * 512]);
    }
  }
  __syncthreads();
  if (c == 0 && tid < 48) {
    bf16x8 z;
#pragma unroll
    for (int j = 0; j < 8; ++j) z[j] = (bf16_t)0.f;
    *(bf16x8*)&rawBC[tid * 8] = z;
  }
  __syncthreads();
  // conv+silu: 128t x 128ch
#pragma unroll 2
  for (int it = 0; it < 64; ++it) {
    int o = tid + it * 256;
    int t = o >> 7, ch = o & 127;
    float a0 = bls[ch];
#pragma unroll
    for (int kk = 0; kk < 4; ++kk)
      a0 = fmaf(wls[ch * 4 + kk], (float)rawBC[(t + kk) * 128 + ch], a0);
    float sv = a0 / (1.f + expf(-a0));
    int slot = ch >> 3;
    int swslot = (slot & 8) | ((slot & 7) ^ (t & 7));
    CB[t * 128 + swslot * 8 + (ch & 7)] = (bf16_t)sv;
    if (c >= 8 && ch >= 64) {
      int n = ch - 64;
      CcG[(((size_t)(b * 4 + (c - 8)) * 128 + t)) * 64 + (((n >> 3) ^ (t & 7)) << 3) + (n & 7)] = (bf16_t)sv;
    }
  }
  __syncthreads();
  // BtG write: transpose B half [n][t^((n&7)<<3)]
  {
    int n = tid & 63, tb = tid >> 6;
#pragma unroll
    for (int s8 = 0; s8 < 4; ++s8) {
      int ts = tb * 32 + s8 * 8;
      bf16x8 v;
#pragma unroll
      for (int e = 0; e < 8; ++e) {
        int t = ts + e;
        int slot = (n >> 3) ^ (t & 7);
        v[e] = CB[t * 128 + slot * 8 + (n & 7)];
      }
      *(bf16x8*)&BtG[((size_t)(b * 12 + c) * 64 + n) * 128 + ((((ts >> 3) ^ (n & 7))) << 3)] = v;
    }
  }
  // S = C@B^T (only needed tiles; tau <= t)
  if (c >= 8) {
    f32x4 sacc[2][8];
#pragma unroll
    for (int tt = 0; tt < 2; ++tt)
#pragma unroll
      for (int ct = 0; ct < 8; ++ct) sacc[tt][ct] = (f32x4){0.f, 0.f, 0.f, 0.f};
    const int ctn = 2 * wid + 2;
#pragma unroll
    for (int kk = 0; kk < 2; ++kk) {
      bf16x8 ca[2];
#pragma unroll
      for (int tt = 0; tt < 2; ++tt) {
        int trow = wid * 32 + tt * 16 + r;
        int slot = (64 + kk * 32 + g * 8) >> 3;
        int sw = (slot & 8) | ((slot & 7) ^ (trow & 7));
        ca[tt] = *(const bf16x8*)&CB[trow * 128 + sw * 8];
      }
#pragma unroll
      for (int ct = 0; ct < 8; ++ct) {
        if (ct < ctn) {
          int taur = ct * 16 + r;
          int sw = ((kk * 4 + g) ^ (taur & 7));
          bf16x8 bb = *(const bf16x8*)&CB[taur * 128 + sw * 8];
          sacc[0][ct] = __builtin_amdgcn_mfma_f32_16x16x32_bf16(ca[0], bb, sacc[0][ct], 0, 0, 0);
          sacc[1][ct] = __builtin_amdgcn_mfma_f32_16x16x32_bf16(ca[1], bb, sacc[1][ct], 0, 0, 0);
        }
      }
    }
    size_t sbase = (size_t)(b * 4 + (c - 8)) * 16384;
#pragma unroll
    for (int tt = 0; tt < 2; ++tt)
#pragma unroll
      for (int ct = 0; ct < 8; ++ct) {
        if (ct < ctn) {
#pragma unroll
          for (int j = 0; j < 4; ++j) {
            int ta = wid * 32 + tt * 16 + g * 4 + j;
            int tau = ct * 16 + r;
            Sg[sbase + ta * 128 + (tau ^ ((ta & 7) << 3))] = (bf16_t)sacc[tt][ct][j];
          }
        }
      }
  }
}

// Pass A: per (b,h,chunk): conv x in LDS, hendT[p][n] = sum_tau w_tau x[tau][p] B[tau][n] via MFMA.
__global__ __launch_bounds__(256)
void ssd_hend(const bf16_t* __restrict__ xbc, const float* __restrict__ dts,
              const float* __restrict__ labuf, const float* __restrict__ cw,
              const float* __restrict__ cb, const bf16_t* __restrict__ BtG,
              bf16_t* __restrict__ hend, float* __restrict__ Lacum,
              float* __restrict__ Ak)
{
  __shared__ __align__(16) bf16_t rawX[136 * 64];   // 17408 B
  __shared__ __align__(16) bf16_t Xt[64 * 128];     // [p][t^((p&7)<<3)]
  __shared__ __align__(16) bf16_t Bt[64 * 128];     // [n][t^((n&7)<<3)]
  __shared__ float wv[128];
  __shared__ float wls[64 * 4];
  __shared__ float bls[64];
  const int c = blockIdx.x;
  const int bh = blockIdx.y;
  const int b = bh >> 4, h = bh & 15;
  const int t0 = c * 128;
  const int tid = threadIdx.x, lane = tid & 63, wid = tid >> 6;
  const int r = lane & 15, g = lane >> 4;

  if (tid < 64) {
    int gch = h * 64 + tid;
#pragma unroll
    for (int k = 0; k < 4; ++k) wls[tid * 4 + k] = cw[gch * 4 + k];
    bls[tid] = cb[gch];
  }
#pragma unroll
  for (int ci = 0; ci < 5; ++ci) {
    int chunk = ci * 4 + wid;
    if (chunk < 17) {
      int F = chunk * 1024 + lane * 16;
      int row = F >> 7, off = F & 127;
      gload16(xbc + (size_t)(b * LL + t0 - 3 + row) * 1152 + h * 64 + off / 2,
              &rawX[chunk * 512]);
    }
  }
#pragma unroll
  for (int ci = 0; ci < 4; ++ci) {
    int chunk = ci * 4 + wid;
    int F = chunk * 1024 + lane * 16;
    gload16(BtG + (size_t)(b * 12 + c) * 8192 + F / 2, &Bt[chunk * 512]);
  }
  __syncthreads();
  if (c == 0 && tid < 24) {
    bf16x8 z;
#pragma unroll
    for (int j = 0; j < 8; ++j) z[j] = (bf16_t)0.f;
    *(bf16x8*)&rawX[tid * 8] = z;
  }
  if (tid < 64) {
    float v0 = labuf[(size_t)(b * LL + t0 + tid) * 16 + h];
    float v1 = labuf[(size_t)(b * LL + t0 + 64 + tid) * 16 + h];
    float d0 = dts[(size_t)(b * LL + t0 + tid) * 16 + h];
    float d1 = dts[(size_t)(b * LL + t0 + 64 + tid) * 16 + h];
#pragma unroll
    for (int d = 1; d < 64; d <<= 1) { float t_ = __shfl(v0, tid - d, 64); if (tid >= d) v0 += t_; }
    float T0 = __shfl(v0, 63, 64);
#pragma unroll
    for (int d = 1; d < 64; d <<= 1) { float t_ = __shfl(v1, tid - d, 64); if (tid >= d) v1 += t_; }
    v1 += T0;
    float Ls = __shfl(v1, 63, 64);
    wv[tid] = expf(Ls - v0) * d0; wv[64 + tid] = expf(Ls - v1) * d1;
    Lacum[(size_t)(bh * 12 + c) * 128 + tid] = v0;
    Lacum[(size_t)(bh * 12 + c) * 128 + 64 + tid] = v1;
    if (tid == 0) Ak[bh * 12 + c] = expf(Ls);
  }
  __syncthreads();
  // conv x -> Xt (vectorized swizzled writes)
  {
    int p = tid & 63, tb = (tid >> 6) * 32;
    float w0 = wls[p * 4], w1 = wls[p * 4 + 1], w2 = wls[p * 4 + 2], w3 = wls[p * 4 + 3];
    float bb0 = bls[p];
    int sw = (p & 7) << 3;
#pragma unroll
    for (int i8 = 0; i8 < 4; ++i8) {
      bf16x8 ov;
#pragma unroll
      for (int e = 0; e < 8; ++e) {
        int t = tb + i8 * 8 + e;
        float a0 = bb0;
        a0 = fmaf(w0, (float)rawX[(t + 0) * 64 + p], a0);
        a0 = fmaf(w1, (float)rawX[(t + 1) * 64 + p], a0);
        a0 = fmaf(w2, (float)rawX[(t + 2) * 64 + p], a0);
        a0 = fmaf(w3, (float)rawX[(t + 3) * 64 + p], a0);
        ov[e] = (bf16_t)(a0 / (1.f + expf(-a0)));
      }
      *(bf16x8*)&Xt[p * 128 + ((tb + i8 * 8) ^ sw)] = ov;
    }
  }
  __syncthreads();
  // hend MFMA
  f32x4 acc[4];
#pragma unroll
  for (int n = 0; n < 4; ++n) acc[n] = (f32x4){0.f, 0.f, 0.f, 0.f};
  const int prow = wid * 16 + r;
#pragma unroll
  for (int kk = 0; kk < 4; ++kk) {
    int k0 = kk * 32 + g * 8;
    bf16x8 xv = *(const bf16x8*)&Xt[prow * 128 + (k0 ^ ((prow & 7) << 3))];
    bf16x8 af;
#pragma unroll
    for (int j = 0; j < 8; ++j) af[j] = (bf16_t)((float)xv[j] * wv[k0 + j]);
#pragma unroll
    for (int nt = 0; nt < 4; ++nt) {
      int nrow = nt * 16 + r;
      bf16x8 bf_ = *(const bf16x8*)&Bt[nrow * 128 + (k0 ^ ((nrow & 7) << 3))];
      acc[nt] = __builtin_amdgcn_mfma_f32_16x16x32_bf16(af, bf_, acc[nt], 0, 0, 0);
    }
  }
  size_t base = ((size_t)(bh * 12 + c)) * 4096;
#pragma unroll
  for (int nt = 0; nt < 4; ++nt)
#pragma unroll
    for (int j = 0; j < 4; ++j)
      hend[base + (size_t)(wid * 16 + g * 4 + j) * 64 + nt * 16 + r] = (bf16_t)acc[nt][j];
}

// Pass B: per (b,h,out-chunk): conv x; G = decay.dt.S (from global S); Y = G@X + exp(La)*(C@hin) + D*x.
__global__ __launch_bounds__(256)
void ssd_y(const bf16_t* __restrict__ xbc, const float* __restrict__ dts,
           const bf16_t* __restrict__ hend, const float* __restrict__ Ak,
           const float* __restrict__ Lacum, const bf16_t* __restrict__ Sg,
           const bf16_t* __restrict__ CcG, const float* __restrict__ cw,
           const float* __restrict__ cb, const float* __restrict__ Dp,
           bf16_t* __restrict__ ybuf)
{
  __shared__ __align__(16) char region0[32768];     // rawX (17408) then Gs (32768)
  __shared__ __align__(16) bf16_t Xt[64 * 128];
  __shared__ __align__(16) bf16_t Cs[128 * 64];
  __shared__ __align__(16) bf16_t hts[64 * 64];
  __shared__ float Lat[128];
  __shared__ float dtv[128];
  __shared__ float wls[64 * 4];
  __shared__ float bls[64];
  bf16_t* rawX = (bf16_t*)region0;
  bf16_t* Gs   = (bf16_t*)region0;
  const int c = 8 + blockIdx.x;
  const int bh = blockIdx.y;
  const int b = bh >> 4, h = bh & 15;
  const int t0 = c * 128;
  const int tid = threadIdx.x, lane = tid & 63, wid = tid >> 6;
  const int r = lane & 15, g = lane >> 4;

  if (tid < 64) {
    int gch = h * 64 + tid;
#pragma unroll
    for (int k = 0; k < 4; ++k) wls[tid * 4 + k] = cw[gch * 4 + k];
    bls[tid] = cb[gch];
  }
  if (tid < 128) {
    Lat[tid] = Lacum[(size_t)(bh * 12 + c) * 128 + tid];
    dtv[tid] = dts[(size_t)(b * LL + t0 + tid) * 16 + h];
  }
#pragma unroll
  for (int ci = 0; ci < 5; ++ci) {
    int chunk = ci * 4 + wid;
    if (chunk < 17) {
      int F = chunk * 1024 + lane * 16;
      int row = F >> 7, off = F & 127;
      gload16(xbc + (size_t)(b * LL + t0 - 3 + row) * 1152 + h * 64 + off / 2,
              &rawX[chunk * 512]);
    }
  }
#pragma unroll
  for (int ci = 0; ci < 4; ++ci) {
    int chunk = ci * 4 + wid;
    int F = chunk * 1024 + lane * 16;
    gload16(CcG + (size_t)(b * 4 + (c - 8)) * 8192 + F / 2, &Cs[chunk * 512]);
  }
  // hin from hend/Ak (global only), write hts swizzled
  {
    float hin[16];
#pragma unroll
    for (int e = 0; e < 16; ++e) hin[e] = 0.f;
    float accp = 1.f;
    for (int k = c - 1; k >= 0; --k) {
      const bf16_t* hp = hend + ((size_t)(bh * 12 + k)) * 4096 + tid * 16;
      bf16x8 e0 = *(const bf16x8*)hp;
      bf16x8 e1 = *(const bf16x8*)(hp + 8);
#pragma unroll
      for (int j = 0; j < 8; ++j) {
        hin[j]     = fmaf(accp, (float)e0[j], hin[j]);
        hin[j + 8] = fmaf(accp, (float)e1[j], hin[j + 8]);
      }
      accp *= Ak[bh * 12 + k];
    }
    int p = tid >> 2, n0 = (tid & 3) * 16;
    bf16x8 o0, o1;
#pragma unroll
    for (int j = 0; j < 8; ++j) { o0[j] = (bf16_t)hin[j]; o1[j] = (bf16_t)hin[j + 8]; }
    int p7 = p & 7;
    *(bf16x8*)&hts[p * 64 + (((n0 >> 3) ^ p7) << 3)] = o0;
    *(bf16x8*)&hts[p * 64 + ((((n0 >> 3) + 1) ^ p7) << 3)] = o1;
  }
  __syncthreads();
  // conv x -> Xt
  {
    int p = tid & 63, tb = (tid >> 6) * 32;
    float w0 = wls[p * 4], w1 = wls[p * 4 + 1], w2 = wls[p * 4 + 2], w3 = wls[p * 4 + 3];
    float bb0 = bls[p];
    int sw = (p & 7) << 3;
#pragma unroll
    for (int i8 = 0; i8 < 4; ++i8) {
      bf16x8 ov;
#pragma unroll
      for (int e = 0; e < 8; ++e) {
        int t = tb + i8 * 8 + e;
        float a0 = bb0;
        a0 = fmaf(w0, (float)rawX[(t + 0) * 64 + p], a0);
        a0 = fmaf(w1, (float)rawX[(t + 1) * 64 + p], a0);
        a0 = fmaf(w2, (float)rawX[(t + 2) * 64 + p], a0);
        a0 = fmaf(w3, (float)rawX[(t + 3) * 64 + p], a0);
        ov[e] = (bf16_t)(a0 / (1.f + expf(-a0)));
      }
      *(bf16x8*)&Xt[p * 128 + ((tb + i8 * 8) ^ sw)] = ov;
    }
  }
  __syncthreads();
  // G build (overlays rawX region)
  {
    size_t sbase = (size_t)(b * 4 + (c - 8)) * 16384;
#pragma unroll
    for (int it = 0; it < 8; ++it) {
      int o = tid + it * 256;
      int ta = o >> 4, sl = o & 15;
      bf16x8 sv = *(const bf16x8*)&Sg[sbase + ta * 128 + sl * 8];
      int tau0 = (sl ^ (ta & 7)) * 8;
      float Lta = Lat[ta];
      bf16x8 gv;
#pragma unroll
      for (int e = 0; e < 8; ++e) {
        int tau = tau0 + e;
        float xa = (tau <= ta) ? (Lta - Lat[tau]) : -1e30f;
        gv[e] = (bf16_t)(expf(xa) * dtv[tau] * (float)sv[e]);
      }
      *(bf16x8*)&Gs[ta * 128 + sl * 8] = gv;
    }
  }
  __syncthreads();

  bf16x8 caf[2][2];
#pragma unroll
  for (int tt = 0; tt < 2; ++tt)
#pragma unroll
    for (int kk = 0; kk < 2; ++kk) {
      int trow = wid * 32 + tt * 16 + r;
      caf[tt][kk] = *(const bf16x8*)&Cs[trow * 64 + ((((kk * 4 + g)) ^ (trow & 7)) << 3)];
    }

  f32x4 accY[2][4], acc2[2][4];
#pragma unroll
  for (int tt = 0; tt < 2; ++tt)
#pragma unroll
    for (int pt = 0; pt < 4; ++pt) {
      accY[tt][pt] = (f32x4){0.f, 0.f, 0.f, 0.f};
      acc2[tt][pt] = (f32x4){0.f, 0.f, 0.f, 0.f};
    }
#pragma unroll
  for (int tt = 0; tt < 2; ++tt) {
    int trow = wid * 32 + tt * 16 + r;
#pragma unroll
    for (int kk = 0; kk < 4; ++kk) {
      if (kk <= wid) {
        int k0 = kk * 32 + g * 8;
        bf16x8 ga = *(const bf16x8*)&Gs[trow * 128 + (k0 ^ ((trow & 7) << 3))];
#pragma unroll
        for (int pt = 0; pt < 4; ++pt) {
          int prow = pt * 16 + r;
          bf16x8 xb = *(const bf16x8*)&Xt[prow * 128 + (k0 ^ ((prow & 7) << 3))];
          accY[tt][pt] = __builtin_amdgcn_mfma_f32_16x16x32_bf16(ga, xb, accY[tt][pt], 0, 0, 0);
        }
      }
    }
#pragma unroll
    for (int kk = 0; kk < 2; ++kk) {
#pragma unroll
      for (int pt = 0; pt < 4; ++pt) {
        int prow = pt * 16 + r;
        bf16x8 hb = *(const bf16x8*)&hts[prow * 64 + ((((kk * 4 + g)) ^ (prow & 7)) << 3)];
        acc2[tt][pt] = __builtin_amdgcn_mfma_f32_16x16x32_bf16(caf[tt][kk], hb, acc2[tt][pt], 0, 0, 0);
      }
    }
  }

  const float Dh = Dp[h];
#pragma unroll
  for (int tt = 0; tt < 2; ++tt) {
#pragma unroll
    for (int j = 0; j < 4; ++j) {
      int trow = wid * 32 + tt * 16 + g * 4 + j;
      float el = expf(Lat[trow]);
      size_t yrow = ((size_t)(b * LTT + (c - 8) * 128 + trow)) << 10;
#pragma unroll
      for (int pt = 0; pt < 4; ++pt) {
        int p = pt * 16 + r;
        float xv = (float)Xt[p * 128 + (trow ^ ((p & 7) << 3))];
        float yv = accY[tt][pt][j] + el * acc2[tt][pt][j] + Dh * xv;
        ybuf[yrow + h * 64 + p] = (bf16_t)yv;
      }
    }
  }
}

__global__ __launch_bounds__(256)
void gate_norm_k(const bf16_t* __restrict__ zbuf, const bf16_t* __restrict__ ybuf,
                 const float* __restrict__ norm_w, bf16_t* __restrict__ yn)
{
  __shared__ float sbuf[4];
  const int row = blockIdx.x;
  const int tid = threadIdx.x;
  bf16x4 yv = *(const bf16x4*)&ybuf[(size_t)row * DINNER + tid * 4];
  bf16x4 zv = *(const bf16x4*)&zbuf[(size_t)row * DINNER + tid * 4];
  float v[4];
#pragma unroll
  for (int c = 0; c < 4; ++c) {
    float y = (float)yv[c], z = (float)zv[c];
    v[c] = y * (z / (1.f + expf(-z)));
  }
  float ss = block_sum(v[0]*v[0] + v[1]*v[1] + v[2]*v[2] + v[3]*v[3], sbuf);
  float inv = rsqrtf(ss * (1.f / 1024.f) + 1e-5f);
  float4 nw = *(const float4*)&norm_w[tid * 4];
  bf16x4 o;
  o[0] = (bf16_t)(v[0] * inv * nw.x); o[1] = (bf16_t)(v[1] * inv * nw.y);
  o[2] = (bf16_t)(v[2] * inv * nw.z); o[3] = (bf16_t)(v[3] * inv * nw.w);
  *(bf16x4*)&yn[(size_t)row * DINNER + tid * 4] = o;
}

__global__ __launch_bounds__(256)
void rms_k(const float* __restrict__ in, bf16_t* __restrict__ out)
{
  __shared__ float sbuf[4];
  const int row = blockIdx.x;
  const int tid = threadIdx.x;
  float2 v = *(const float2*)&in[(size_t)row * DMODEL + tid * 2];
  float ss = block_sum(v.x * v.x + v.y * v.y, sbuf);
  float inv = rsqrtf(ss * (1.f / 512.f) + 1e-6f);
  bf16x2 o; o[0] = (bf16_t)(v.x * inv); o[1] = (bf16_t)(v.y * inv);
  *(bf16x2*)&out[(size_t)row * DMODEL + tid * 2] = o;
}

extern "C" void kernel_launch(void* const* d_in, const int* in_sizes, int n_in,
                              void* d_out, int out_size, void* d_ws, size_t ws_size,
                              hipStream_t stream)
{
  const float* tgt        = (const float*)d_in[0];
  const float* memory     = (const float*)d_in[1];
  const float* mem_mask   = (const float*)d_in[2];
  const float* tgt_mask   = (const float*)d_in[3];
  const float* in_proj_w  = (const float*)d_in[4];
  const float* conv_w     = (const float*)d_in[5];
  const float* conv_b     = (const float*)d_in[6];
  const float* dt_bias    = (const float*)d_in[7];
  const float* A_log      = (const float*)d_in[8];
  const float* Dp         = (const float*)d_in[9];
  const float* norm_w     = (const float*)d_in[10];
  const float* out_proj_w = (const float*)d_in[11];
  const float* fc1_w      = (const float*)d_in[12];
  const float* fc1_b      = (const float*)d_in[13];
  const float* fc2_w      = (const float*)d_in[14];
  const float* fc2_b      = (const float*)d_in[15];

  char* wsb = (char*)d_ws;
  bf16_t* u     = (bf16_t*)(wsb + 0);            // 25,165,824 B
  bf16_t* zbuf  = (bf16_t*)(wsb + 25165824);     // 16,777,216 B
  bf16_t* xbc   = (bf16_t*)(wsb + 41943040);     // 56,623,104 B
  float*  dts   = (float*)(wsb + 98566144);      // 1,572,864 B
  float*  labuf = (float*)(wsb + 100139008);     // 1,572,864 B
  float*  tgtm  = (float*)(wsb + 101711872);     // 16,777,216 B
  bf16_t* hend  = (bf16_t*)(wsb + 118489088);    // 25,165,824 B
  float*  Lacum = (float*)(wsb + 143667200);     // 1,572,864 B
  float*  Akb   = (float*)(wsb + 145240064);     // 12,288 B
  bf16_t* BtG   = (bf16_t*)(wsb + 145252352);    // 3,145,728 B
  bf16_t* Sg    = (bf16_t*)(wsb + 148398080);    // 2,097,152 B
  bf16_t* CcG   = (bf16_t*)(wsb + 150495232);    // 1,048,576 B
  bf16_t* wip   = (bf16_t*)(wsb + 160444416);    // weights (bf16)
  bf16_t* wop   = wip + 1122304;
  bf16_t* wf1   = wop + 524288;
  bf16_t* wf2   = wf1 + 1048576;
  // overlays:
  bf16_t* ybuf  = (bf16_t*)(wsb + 0);            // over u (dead after in_proj)
  bf16_t* yn    = (bf16_t*)(wsb + 41943040);     // over xbc (dead after ssd_y)
  float*  tres  = (float*)(wsb + 58720256);      // over xbc+16M
  bf16_t* t1    = (bf16_t*)(wsb + 75497472);     // over xbc+32M
  bf16_t* hbuf  = (bf16_t*)(wsb + 0);            // over u+zbuf (dead after gate_norm)
  float* outp = (float*)d_out;

  cvt_w<<<1096, 256, 0, stream>>>(in_proj_w, wip, 1122304);
  cvt_w<<<512, 256, 0, stream>>>(out_proj_w, wop, 524288);
  cvt_w<<<1024, 256, 0, stream>>>(fc1_w, wf1, 1048576);
  cvt_w<<<1024, 256, 0, stream>>>(fc2_w, wf2, 1048576);
  prep_u<<<BB * LL, 256, 0, stream>>>(tgt, memory, mem_mask, tgt_mask, u, tgtm);
  gemm_abf<4><<<dim3(18, 192), 256, 0, stream>>>(u, wip, BB * LL, DIPROJ, DMODEL,
      nullptr, nullptr, nullptr, nullptr, zbuf, xbc, dts, labuf, dt_bias, A_log);
  sbc_k<<<dim3(12, BB), 256, 0, stream>>>(xbc, conv_w, conv_b, BtG, Sg, CcG);
  ssd_hend<<<dim3(12, BB * NH), 256, 0, stream>>>(xbc, dts, labuf, conv_w, conv_b,
      BtG, hend, Lacum, Akb);
  ssd_y<<<dim3(4, BB * NH), 256, 0, stream>>>(xbc, dts, hend, Akb, Lacum, Sg, CcG,
      conv_w, conv_b, Dp, ybuf);
  gate_norm_k<<<BB * LTT, 256, 0, stream>>>(zbuf, ybuf, norm_w, yn);
  gemm_abf<3><<<dim3(4, 64), 256, 0, stream>>>(yn, wop, BB * LTT, DMODEL, DINNER,
      tres, nullptr, nullptr, tgtm, nullptr, nullptr, nullptr, nullptr, nullptr, nullptr);
  rms_k<<<BB * LTT, 256, 0, stream>>>(tres, t1);
  gemm_abf<1><<<dim3(16, 64), 256, 0, stream>>>(t1, wf1, BB * LTT, DFF2, DMODEL,
      nullptr, hbuf, fc1_b, nullptr, nullptr, nullptr, nullptr, nullptr, nullptr, nullptr);
  gemm_abf<2><<<dim3(4, 64), 256, 0, stream>>>(hbuf, wf2, BB * LTT, DMODEL, DFF2,
      outp, nullptr, fc2_b, tres, nullptr, nullptr, nullptr, nullptr, nullptr, nullptr);
}

// Round 9
// 301.382 us; speedup vs baseline: 1.1233x; 1.1233x over previous
//
#include <hip/hip_runtime.h>
#include <cstddef>

#define BB 16
#define LMM 1024
#define LTT 512
#define LL 1536
#define DMODEL 512
#define DINNER 1024
#define NH 16
#define DIPROJ 2192
#define DFF2 2048

typedef __bf16 bf16_t;
typedef bf16_t bf16x2 __attribute__((ext_vector_type(2)));
typedef bf16_t bf16x4 __attribute__((ext_vector_type(4)));
typedef bf16_t bf16x8 __attribute__((ext_vector_type(8)));
typedef float f32x4 __attribute__((ext_vector_type(4)));

typedef __attribute__((address_space(3))) void lds_void;
typedef const __attribute__((address_space(1))) void glb_void;

__device__ __forceinline__ void gload16(const void* g, void* l) {
  __builtin_amdgcn_global_load_lds((glb_void*)g, (lds_void*)l, 16, 0, 0);
}

__device__ inline float block_sum(float v, float* sbuf) {
#pragma unroll
  for (int off = 32; off > 0; off >>= 1) v += __shfl_xor(v, off, 64);
  int w = threadIdx.x >> 6;
  if ((threadIdx.x & 63) == 0) sbuf[w] = v;
  __syncthreads();
  return sbuf[0] + sbuf[1] + sbuf[2] + sbuf[3];
}

// all 4 weight matrices -> bf16, contiguous dst
__global__ __launch_bounds__(256)
void cvt_all(const float* __restrict__ s0, const float* __restrict__ s1,
             const float* __restrict__ s2, const float* __restrict__ s3,
             bf16_t* __restrict__ dst)
{
  int i = (blockIdx.x * 256 + threadIdx.x) * 4;
  if (i >= 3743744) return;
  const float* src;
  int off;
  if (i < 1122304)      { src = s0; off = i; }
  else if (i < 1646592) { src = s1; off = i - 1122304; }
  else if (i < 2695168) { src = s2; off = i - 1646592; }
  else                  { src = s3; off = i - 2695168; }
  float4 v = *(const float4*)&src[off];
  bf16x4 o;
  o[0] = (bf16_t)v.x; o[1] = (bf16_t)v.y; o[2] = (bf16_t)v.z; o[3] = (bf16_t)v.w;
  *(bf16x4*)&dst[i] = o;
}

__global__ __launch_bounds__(256)
void prep_u(const float* __restrict__ tgt, const float* __restrict__ memory,
            const float* __restrict__ mem_mask, const float* __restrict__ tgt_mask,
            bf16_t* __restrict__ u, float* __restrict__ tgtm)
{
  __shared__ float sbuf[4];
  const int row = blockIdx.x;              // b*LL + t
  const int b = row / LL;
  const int t = row - b * LL;
  const int tid = threadIdx.x;
  if (t < LMM) {
    float m = mem_mask[b * LMM + t];
    float s = m * m;
    const float* src = memory + ((size_t)b * LMM + t) * DMODEL;
    float2 v = *(const float2*)&src[tid * 2];
    bf16x2 o; o[0] = (bf16_t)(v.x * s); o[1] = (bf16_t)(v.y * s);
    *(bf16x2*)&u[(size_t)row * DMODEL + tid * 2] = o;
  } else {
    const int tt = t - LMM;
    float mk = tgt_mask[b * LTT + tt];
    const float* src = tgt + ((size_t)b * LTT + tt) * DMODEL;
    float2 v = *(const float2*)&src[tid * 2];
    v.x *= mk; v.y *= mk;
    *(float2*)&tgtm[((size_t)b * LTT + tt) * DMODEL + tid * 2] = v;
    float ss = block_sum(v.x * v.x + v.y * v.y, sbuf);
    float inv = rsqrtf(ss * (1.0f / 512.0f) + 1e-6f) * mk;
    bf16x2 o; o[0] = (bf16_t)(v.x * inv); o[1] = (bf16_t)(v.y * inv);
    *(bf16x2*)&u[(size_t)row * DMODEL + tid * 2] = o;
  }
}

// 128x128 tile GEMM (single-buffer, gload_lds, XOR swizzle, XCD block swizzle).
// EPI: 2 fc2 (+bias+res, fp32 out), 3 out_proj (+res, fp32 out)
template<int EPI>
__global__ __launch_bounds__(256)
void gemm_abf(const bf16_t* __restrict__ A, const bf16_t* __restrict__ W,
              int M, int N, int K,
              float* __restrict__ Cf, const float* __restrict__ bias,
              const float* __restrict__ res)
{
  const int nbx = gridDim.x;
  const int nwg = nbx * gridDim.y;
  int flat = blockIdx.y * nbx + blockIdx.x;
  int swz = (flat & 7) * (nwg >> 3) + (flat >> 3);
  const int m0 = (swz / nbx) * 128;
  const int n0 = (swz % nbx) * 128;
  __shared__ __align__(16) bf16_t As[128 * 64];
  __shared__ __align__(16) bf16_t Bs[128 * 64];
  const int tid = threadIdx.x;
  const int lane = tid & 63;
  const int wid = tid >> 6;
  const int wr = (wid >> 1) * 64, wc = (wid & 1) * 64;
  const int r = lane & 15;
  const int g = lane >> 4;
  const int r7 = r & 7;
  const int lrow = lane >> 3;
  const int sslot = (lane & 7) ^ lrow;

  int arow[4], brow[4];
#pragma unroll
  for (int ci = 0; ci < 4; ++ci) {
    int tr = wid * 32 + ci * 8 + lrow;
    arow[ci] = m0 + tr;
    int bn = n0 + tr;
    brow[ci] = bn < N ? bn : N - 1;
  }

  f32x4 acc[4][4];
#pragma unroll
  for (int m = 0; m < 4; ++m)
#pragma unroll
    for (int n = 0; n < 4; ++n) acc[m][n] = (f32x4){0.f, 0.f, 0.f, 0.f};

  for (int kt = 0; kt < K; kt += 64) {
#pragma unroll
    for (int ci = 0; ci < 4; ++ci) {
      int chunk = wid * 4 + ci;
      gload16(A + (size_t)arow[ci] * K + kt + sslot * 8, &As[chunk * 512]);
      gload16(W + (size_t)brow[ci] * K + kt + sslot * 8, &Bs[chunk * 512]);
    }
    __syncthreads();
#pragma unroll
    for (int c = 0; c < 2; ++c) {
      bf16x8 af[4], bfr[4];
#pragma unroll
      for (int m = 0; m < 4; ++m) {
        int row = wr + m * 16 + r;
        af[m] = *(const bf16x8*)&As[row * 64 + (((c * 4 + g) ^ r7) * 8)];
      }
#pragma unroll
      for (int n = 0; n < 4; ++n) {
        int row = wc + n * 16 + r;
        bfr[n] = *(const bf16x8*)&Bs[row * 64 + (((c * 4 + g) ^ r7) * 8)];
      }
#pragma unroll
      for (int m = 0; m < 4; ++m)
#pragma unroll
        for (int n = 0; n < 4; ++n)
          acc[m][n] = __builtin_amdgcn_mfma_f32_16x16x32_bf16(af[m], bfr[n], acc[m][n], 0, 0, 0);
    }
    __syncthreads();
  }

#pragma unroll
  for (int m = 0; m < 4; ++m) {
#pragma unroll
    for (int n = 0; n < 4; ++n) {
      int gcol = n0 + wc + n * 16 + r;
      if (gcol >= N) continue;
#pragma unroll
      for (int j = 0; j < 4; ++j) {
        float v = acc[m][n][j];
        int grow = m0 + wr + m * 16 + g * 4 + j;
        if (EPI == 2) v += bias[gcol] + res[(size_t)grow * N + gcol];
        else          v += res[(size_t)grow * N + gcol];
        Cf[(size_t)grow * N + gcol] = v;
      }
    }
  }
}

// 256x128 tile GEMM, 512 threads (8 waves, 4M x 2N), single-buffer, gload_lds, swizzles.
// EPI: 1 fc1 (+bias, exact gelu, bf16 out), 4 in_proj split.
template<int EPI>
__global__ __launch_bounds__(512)
void gemm_big(const bf16_t* __restrict__ A, const bf16_t* __restrict__ W,
              int M, int N, int K,
              bf16_t* __restrict__ Cb, const float* __restrict__ bias,
              bf16_t* __restrict__ zbuf, bf16_t* __restrict__ xbc,
              float* __restrict__ dts, float* __restrict__ labuf,
              const float* __restrict__ dt_bias, const float* __restrict__ A_log)
{
  const int nbx = gridDim.x;
  const int nwg = nbx * gridDim.y;
  int flat = blockIdx.y * nbx + blockIdx.x;
  int swz = (flat & 7) * (nwg >> 3) + (flat >> 3);
  const int m0 = (swz / nbx) * 256;
  const int n0 = (swz % nbx) * 128;
  int bq = 0, tbase = 0;
  if (EPI == 4) {
    bq = m0 / LL; tbase = m0 - bq * LL;            // 1536 = 6*256
    if (n0 + 128 <= DINNER && tbase + 256 <= LMM) return;  // z-cols x mem-rows dead
  }
  __shared__ __align__(16) bf16_t As[256 * 64];    // 32 KB
  __shared__ __align__(16) bf16_t Bs[128 * 64];    // 16 KB
  const int tid = threadIdx.x;
  const int lane = tid & 63;
  const int wid = tid >> 6;                        // 0..7
  const int wr = (wid >> 1) * 64;                  // M-block base: 0,64,128,192
  const int wc = (wid & 1) * 64;                   // N-block base: 0,64
  const int r = lane & 15;
  const int g = lane >> 4;
  const int r7 = r & 7;
  const int lrow = lane >> 3;
  const int sslot = (lane & 7) ^ lrow;

  int arow[4], brow[2];
#pragma unroll
  for (int ci = 0; ci < 4; ++ci) arow[ci] = m0 + wid * 32 + ci * 8 + lrow;
#pragma unroll
  for (int ci = 0; ci < 2; ++ci) {
    int bn = n0 + wid * 16 + ci * 8 + lrow;
    brow[ci] = bn < N ? bn : N - 1;
  }

  f32x4 acc[4][4];
#pragma unroll
  for (int m = 0; m < 4; ++m)
#pragma unroll
    for (int n = 0; n < 4; ++n) acc[m][n] = (f32x4){0.f, 0.f, 0.f, 0.f};

  for (int kt = 0; kt < K; kt += 64) {
#pragma unroll
    for (int ci = 0; ci < 4; ++ci)
      gload16(A + (size_t)arow[ci] * K + kt + sslot * 8, &As[(wid * 4 + ci) * 512]);
#pragma unroll
    for (int ci = 0; ci < 2; ++ci)
      gload16(W + (size_t)brow[ci] * K + kt + sslot * 8, &Bs[(wid * 2 + ci) * 512]);
    __syncthreads();
#pragma unroll
    for (int c = 0; c < 2; ++c) {
      bf16x8 af[4], bfr[4];
#pragma unroll
      for (int m = 0; m < 4; ++m) {
        int row = wr + m * 16 + r;                 // 0..255 across the 4 M-blocks
        af[m] = *(const bf16x8*)&As[row * 64 + (((c * 4 + g) ^ r7) * 8)];
      }
#pragma unroll
      for (int n = 0; n < 4; ++n) {
        int row = wc + n * 16 + r;
        bfr[n] = *(const bf16x8*)&Bs[row * 64 + (((c * 4 + g) ^ r7) * 8)];
      }
#pragma unroll
      for (int m = 0; m < 4; ++m)
#pragma unroll
        for (int n = 0; n < 4; ++n)
          acc[m][n] = __builtin_amdgcn_mfma_f32_16x16x32_bf16(af[m], bfr[n], acc[m][n], 0, 0, 0);
    }
    __syncthreads();
  }

#pragma unroll
  for (int m = 0; m < 4; ++m) {
#pragma unroll
    for (int n = 0; n < 4; ++n) {
      int gcol = n0 + wc + n * 16 + r;
      if (gcol >= N) continue;
#pragma unroll
      for (int j = 0; j < 4; ++j) {
        float v = acc[m][n][j];
        int lrow2 = wr + m * 16 + g * 4 + j;       // 0..255
        if (EPI == 4) {
          int t = tbase + lrow2;
          if (gcol < DINNER) {
            if (t >= LMM)
              zbuf[(((size_t)(bq * LTT + t - LMM)) << 10) + gcol] = (bf16_t)v;
          } else if (gcol < DINNER + 1152) {
            xbc[(size_t)(bq * LL + t) * 1152 + (gcol - DINNER)] = (bf16_t)v;
          } else {
            int h = gcol - 2176;
            float raw = v + dt_bias[h];
            float d = raw > 20.f ? raw : log1pf(expf(raw));
            size_t ix = (size_t)(bq * LL + t) * 16 + h;
            dts[ix] = d;
            labuf[ix] = -expf(A_log[h]) * d;       // log a
          }
        } else {
          int grow = m0 + lrow2;
          v += bias[gcol];
          v = 0.5f * v * (1.f + erff(v * 0.70710678f));
          Cb[(size_t)grow * N + gcol] = (bf16_t)v;
        }
      }
    }
  }
}

// Per (chunk, b): conv+silu B/C (shared across heads); write BtG [b][c][n][t^] (bf16),
// and for c>=8: CcG [b][c-8][t][n^] and S = C@B^T (triangular) in G-layout.
__global__ __launch_bounds__(256)
void sbc_k(const bf16_t* __restrict__ xbc, const float* __restrict__ cw,
           const float* __restrict__ cb, bf16_t* __restrict__ BtG,
           bf16_t* __restrict__ Sg, bf16_t* __restrict__ CcG)
{
  __shared__ __align__(16) bf16_t rawBC[132 * 128];
  __shared__ __align__(16) bf16_t CB[128 * 128];
  __shared__ float wls[128 * 4];
  __shared__ float bls[128];
  const int c = blockIdx.x, b = blockIdx.y;
  const int t0 = c * 128;
  const int tid = threadIdx.x, lane = tid & 63, wid = tid >> 6;
  const int r = lane & 15, g = lane >> 4;

  if (tid < 128) {
    int gch = 1024 + tid;
#pragma unroll
    for (int k = 0; k < 4; ++k) wls[tid * 4 + k] = cw[gch * 4 + k];
    bls[tid] = cb[gch];
  }
#pragma unroll
  for (int ci = 0; ci < 9; ++ci) {
    int chunk = ci * 4 + wid;
    if (chunk < 33) {
      int F = chunk * 1024 + lane * 16;
      int row = F >> 8, off = F & 255;
      gload16(xbc + (size_t)(b * LL + t0 - 3 + row) * 1152 + 1024 + off / 2,
              &rawBC[chunk * 512]);
    }
  }
  __syncthreads();
  if (c == 0 && tid < 48) {
    bf16x8 z;
#pragma unroll
    for (int j = 0; j < 8; ++j) z[j] = (bf16_t)0.f;
    *(bf16x8*)&rawBC[tid * 8] = z;
  }
  __syncthreads();
#pragma unroll 2
  for (int it = 0; it < 64; ++it) {
    int o = tid + it * 256;
    int t = o >> 7, ch = o & 127;
    float a0 = bls[ch];
#pragma unroll
    for (int kk = 0; kk < 4; ++kk)
      a0 = fmaf(wls[ch * 4 + kk], (float)rawBC[(t + kk) * 128 + ch], a0);
    float sv = a0 / (1.f + expf(-a0));
    int slot = ch >> 3;
    int swslot = (slot & 8) | ((slot & 7) ^ (t & 7));
    CB[t * 128 + swslot * 8 + (ch & 7)] = (bf16_t)sv;
    if (c >= 8 && ch >= 64) {
      int n = ch - 64;
      CcG[(((size_t)(b * 4 + (c - 8)) * 128 + t)) * 64 + (((n >> 3) ^ (t & 7)) << 3) + (n & 7)] = (bf16_t)sv;
    }
  }
  __syncthreads();
  {
    int n = tid & 63, tb = tid >> 6;
#pragma unroll
    for (int s8 = 0; s8 < 4; ++s8) {
      int ts = tb * 32 + s8 * 8;
      bf16x8 v;
#pragma unroll
      for (int e = 0; e < 8; ++e) {
        int t = ts + e;
        int slot = (n >> 3) ^ (t & 7);
        v[e] = CB[t * 128 + slot * 8 + (n & 7)];
      }
      *(bf16x8*)&BtG[((size_t)(b * 12 + c) * 64 + n) * 128 + ((((ts >> 3) ^ (n & 7))) << 3)] = v;
    }
  }
  if (c >= 8) {
    f32x4 sacc[2][8];
#pragma unroll
    for (int tt = 0; tt < 2; ++tt)
#pragma unroll
      for (int ct = 0; ct < 8; ++ct) sacc[tt][ct] = (f32x4){0.f, 0.f, 0.f, 0.f};
    const int ctn = 2 * wid + 2;
#pragma unroll
    for (int kk = 0; kk < 2; ++kk) {
      bf16x8 ca[2];
#pragma unroll
      for (int tt = 0; tt < 2; ++tt) {
        int trow = wid * 32 + tt * 16 + r;
        int slot = (64 + kk * 32 + g * 8) >> 3;
        int sw = (slot & 8) | ((slot & 7) ^ (trow & 7));
        ca[tt] = *(const bf16x8*)&CB[trow * 128 + sw * 8];
      }
#pragma unroll
      for (int ct = 0; ct < 8; ++ct) {
        if (ct < ctn) {
          int taur = ct * 16 + r;
          int sw = ((kk * 4 + g) ^ (taur & 7));
          bf16x8 bb = *(const bf16x8*)&CB[taur * 128 + sw * 8];
          sacc[0][ct] = __builtin_amdgcn_mfma_f32_16x16x32_bf16(ca[0], bb, sacc[0][ct], 0, 0, 0);
          sacc[1][ct] = __builtin_amdgcn_mfma_f32_16x16x32_bf16(ca[1], bb, sacc[1][ct], 0, 0, 0);
        }
      }
    }
    size_t sbase = (size_t)(b * 4 + (c - 8)) * 16384;
#pragma unroll
    for (int tt = 0; tt < 2; ++tt)
#pragma unroll
      for (int ct = 0; ct < 8; ++ct) {
        if (ct < ctn) {
#pragma unroll
          for (int j = 0; j < 4; ++j) {
            int ta = wid * 32 + tt * 16 + g * 4 + j;
            int tau = ct * 16 + r;
            Sg[sbase + ta * 128 + (tau ^ ((ta & 7) << 3))] = (bf16_t)sacc[tt][ct][j];
          }
        }
      }
  }
}

// Pass A: per (b,h,chunk): conv x in LDS, hendT[p][n] = sum_tau w_tau x[tau][p] B[tau][n] via MFMA.
__global__ __launch_bounds__(256)
void ssd_hend(const bf16_t* __restrict__ xbc, const float* __restrict__ dts,
              const float* __restrict__ labuf, const float* __restrict__ cw,
              const float* __restrict__ cb, const bf16_t* __restrict__ BtG,
              bf16_t* __restrict__ hend, float* __restrict__ Lacum,
              float* __restrict__ Ak)
{
  __shared__ __align__(16) bf16_t rawX[136 * 64];
  __shared__ __align__(16) bf16_t Xt[64 * 128];
  __shared__ __align__(16) bf16_t Bt[64 * 128];
  __shared__ float wv[128];
  __shared__ float wls[64 * 4];
  __shared__ float bls[64];
  const int c = blockIdx.x;
  const int bh = blockIdx.y;
  const int b = bh >> 4, h = bh & 15;
  const int t0 = c * 128;
  const int tid = threadIdx.x, lane = tid & 63, wid = tid >> 6;
  const int r = lane & 15, g = lane >> 4;

  if (tid < 64) {
    int gch = h * 64 + tid;
#pragma unroll
    for (int k = 0; k < 4; ++k) wls[tid * 4 + k] = cw[gch * 4 + k];
    bls[tid] = cb[gch];
  }
#pragma unroll
  for (int ci = 0; ci < 5; ++ci) {
    int chunk = ci * 4 + wid;
    if (chunk < 17) {
      int F = chunk * 1024 + lane * 16;
      int row = F >> 7, off = F & 127;
      gload16(xbc + (size_t)(b * LL + t0 - 3 + row) * 1152 + h * 64 + off / 2,
              &rawX[chunk * 512]);
    }
  }
#pragma unroll
  for (int ci = 0; ci < 4; ++ci) {
    int chunk = ci * 4 + wid;
    int F = chunk * 1024 + lane * 16;
    gload16(BtG + (size_t)(b * 12 + c) * 8192 + F / 2, &Bt[chunk * 512]);
  }
  __syncthreads();
  if (c == 0 && tid < 24) {
    bf16x8 z;
#pragma unroll
    for (int j = 0; j < 8; ++j) z[j] = (bf16_t)0.f;
    *(bf16x8*)&rawX[tid * 8] = z;
  }
  if (tid < 64) {
    float v0 = labuf[(size_t)(b * LL + t0 + tid) * 16 + h];
    float v1 = labuf[(size_t)(b * LL + t0 + 64 + tid) * 16 + h];
    float d0 = dts[(size_t)(b * LL + t0 + tid) * 16 + h];
    float d1 = dts[(size_t)(b * LL + t0 + 64 + tid) * 16 + h];
#pragma unroll
    for (int d = 1; d < 64; d <<= 1) { float t_ = __shfl(v0, tid - d, 64); if (tid >= d) v0 += t_; }
    float T0 = __shfl(v0, 63, 64);
#pragma unroll
    for (int d = 1; d < 64; d <<= 1) { float t_ = __shfl(v1, tid - d, 64); if (tid >= d) v1 += t_; }
    v1 += T0;
    float Ls = __shfl(v1, 63, 64);
    wv[tid] = expf(Ls - v0) * d0; wv[64 + tid] = expf(Ls - v1) * d1;
    Lacum[(size_t)(bh * 12 + c) * 128 + tid] = v0;
    Lacum[(size_t)(bh * 12 + c) * 128 + 64 + tid] = v1;
    if (tid == 0) Ak[bh * 12 + c] = expf(Ls);
  }
  __syncthreads();
  {
    int p = tid & 63, tb = (tid >> 6) * 32;
    float w0 = wls[p * 4], w1 = wls[p * 4 + 1], w2 = wls[p * 4 + 2], w3 = wls[p * 4 + 3];
    float bb0 = bls[p];
    int sw = (p & 7) << 3;
#pragma unroll
    for (int i8 = 0; i8 < 4; ++i8) {
      bf16x8 ov;
#pragma unroll
      for (int e = 0; e < 8; ++e) {
        int t = tb + i8 * 8 + e;
        float a0 = bb0;
        a0 = fmaf(w0, (float)rawX[(t + 0) * 64 + p], a0);
        a0 = fmaf(w1, (float)rawX[(t + 1) * 64 + p], a0);
        a0 = fmaf(w2, (float)rawX[(t + 2) * 64 + p], a0);
        a0 = fmaf(w3, (float)rawX[(t + 3) * 64 + p], a0);
        ov[e] = (bf16_t)(a0 / (1.f + expf(-a0)));
      }
      *(bf16x8*)&Xt[p * 128 + ((tb + i8 * 8) ^ sw)] = ov;
    }
  }
  __syncthreads();
  f32x4 acc[4];
#pragma unroll
  for (int n = 0; n < 4; ++n) acc[n] = (f32x4){0.f, 0.f, 0.f, 0.f};
  const int prow = wid * 16 + r;
#pragma unroll
  for (int kk = 0; kk < 4; ++kk) {
    int k0 = kk * 32 + g * 8;
    bf16x8 xv = *(const bf16x8*)&Xt[prow * 128 + (k0 ^ ((prow & 7) << 3))];
    bf16x8 af;
#pragma unroll
    for (int j = 0; j < 8; ++j) af[j] = (bf16_t)((float)xv[j] * wv[k0 + j]);
#pragma unroll
    for (int nt = 0; nt < 4; ++nt) {
      int nrow = nt * 16 + r;
      bf16x8 bf_ = *(const bf16x8*)&Bt[nrow * 128 + (k0 ^ ((nrow & 7) << 3))];
      acc[nt] = __builtin_amdgcn_mfma_f32_16x16x32_bf16(af, bf_, acc[nt], 0, 0, 0);
    }
  }
  size_t base = ((size_t)(bh * 12 + c)) * 4096;
#pragma unroll
  for (int nt = 0; nt < 4; ++nt)
#pragma unroll
    for (int j = 0; j < 4; ++j)
      hend[base + (size_t)(wid * 16 + g * 4 + j) * 64 + nt * 16 + r] = (bf16_t)acc[nt][j];
}

// Pass B: per (b,h,out-chunk): conv x; G = decay.dt.S; Y = G@X + exp(La)*(C@hin) + D*x.
__global__ __launch_bounds__(256)
void ssd_y(const bf16_t* __restrict__ xbc, const float* __restrict__ dts,
           const bf16_t* __restrict__ hend, const float* __restrict__ Ak,
           const float* __restrict__ Lacum, const bf16_t* __restrict__ Sg,
           const bf16_t* __restrict__ CcG, const float* __restrict__ cw,
           const float* __restrict__ cb, const float* __restrict__ Dp,
           bf16_t* __restrict__ ybuf)
{
  __shared__ __align__(16) char region0[32768];
  __shared__ __align__(16) bf16_t Xt[64 * 128];
  __shared__ __align__(16) bf16_t Cs[128 * 64];
  __shared__ __align__(16) bf16_t hts[64 * 64];
  __shared__ float Lat[128];
  __shared__ float dtv[128];
  __shared__ float wls[64 * 4];
  __shared__ float bls[64];
  bf16_t* rawX = (bf16_t*)region0;
  bf16_t* Gs   = (bf16_t*)region0;
  const int c = 8 + blockIdx.x;
  const int bh = blockIdx.y;
  const int b = bh >> 4, h = bh & 15;
  const int t0 = c * 128;
  const int tid = threadIdx.x, lane = tid & 63, wid = tid >> 6;
  const int r = lane & 15, g = lane >> 4;

  if (tid < 64) {
    int gch = h * 64 + tid;
#pragma unroll
    for (int k = 0; k < 4; ++k) wls[tid * 4 + k] = cw[gch * 4 + k];
    bls[tid] = cb[gch];
  }
  if (tid < 128) {
    Lat[tid] = Lacum[(size_t)(bh * 12 + c) * 128 + tid];
    dtv[tid] = dts[(size_t)(b * LL + t0 + tid) * 16 + h];
  }
#pragma unroll
  for (int ci = 0; ci < 5; ++ci) {
    int chunk = ci * 4 + wid;
    if (chunk < 17) {
      int F = chunk * 1024 + lane * 16;
      int row = F >> 7, off = F & 127;
      gload16(xbc + (size_t)(b * LL + t0 - 3 + row) * 1152 + h * 64 + off / 2,
              &rawX[chunk * 512]);
    }
  }
#pragma unroll
  for (int ci = 0; ci < 4; ++ci) {
    int chunk = ci * 4 + wid;
    int F = chunk * 1024 + lane * 16;
    gload16(CcG + (size_t)(b * 4 + (c - 8)) * 8192 + F / 2, &Cs[chunk * 512]);
  }
  {
    float hin[16];
#pragma unroll
    for (int e = 0; e < 16; ++e) hin[e] = 0.f;
    float accp = 1.f;
    for (int k = c - 1; k >= 0; --k) {
      const bf16_t* hp = hend + ((size_t)(bh * 12 + k)) * 4096 + tid * 16;
      bf16x8 e0 = *(const bf16x8*)hp;
      bf16x8 e1 = *(const bf16x8*)(hp + 8);
#pragma unroll
      for (int j = 0; j < 8; ++j) {
        hin[j]     = fmaf(accp, (float)e0[j], hin[j]);
        hin[j + 8] = fmaf(accp, (float)e1[j], hin[j + 8]);
      }
      accp *= Ak[bh * 12 + k];
    }
    int p = tid >> 2, n0 = (tid & 3) * 16;
    bf16x8 o0, o1;
#pragma unroll
    for (int j = 0; j < 8; ++j) { o0[j] = (bf16_t)hin[j]; o1[j] = (bf16_t)hin[j + 8]; }
    int p7 = p & 7;
    *(bf16x8*)&hts[p * 64 + (((n0 >> 3) ^ p7) << 3)] = o0;
    *(bf16x8*)&hts[p * 64 + ((((n0 >> 3) + 1) ^ p7) << 3)] = o1;
  }
  __syncthreads();
  {
    int p = tid & 63, tb = (tid >> 6) * 32;
    float w0 = wls[p * 4], w1 = wls[p * 4 + 1], w2 = wls[p * 4 + 2], w3 = wls[p * 4 + 3];
    float bb0 = bls[p];
    int sw = (p & 7) << 3;
#pragma unroll
    for (int i8 = 0; i8 < 4; ++i8) {
      bf16x8 ov;
#pragma unroll
      for (int e = 0; e < 8; ++e) {
        int t = tb + i8 * 8 + e;
        float a0 = bb0;
        a0 = fmaf(w0, (float)rawX[(t + 0) * 64 + p], a0);
        a0 = fmaf(w1, (float)rawX[(t + 1) * 64 + p], a0);
        a0 = fmaf(w2, (float)rawX[(t + 2) * 64 + p], a0);
        a0 = fmaf(w3, (float)rawX[(t + 3) * 64 + p], a0);
        ov[e] = (bf16_t)(a0 / (1.f + expf(-a0)));
      }
      *(bf16x8*)&Xt[p * 128 + ((tb + i8 * 8) ^ sw)] = ov;
    }
  }
  __syncthreads();
  {
    size_t sbase = (size_t)(b * 4 + (c - 8)) * 16384;
#pragma unroll
    for (int it = 0; it < 8; ++it) {
      int o = tid + it * 256;
      int ta = o >> 4, sl = o & 15;
      bf16x8 sv = *(const bf16x8*)&Sg[sbase + ta * 128 + sl * 8];
      int tau0 = (sl ^ (ta & 7)) * 8;
      float Lta = Lat[ta];
      bf16x8 gv;
#pragma unroll
      for (int e = 0; e < 8; ++e) {
        int tau = tau0 + e;
        float xa = (tau <= ta) ? (Lta - Lat[tau]) : -1e30f;
        gv[e] = (bf16_t)(expf(xa) * dtv[tau] * (float)sv[e]);
      }
      *(bf16x8*)&Gs[ta * 128 + sl * 8] = gv;
    }
  }
  __syncthreads();

  bf16x8 caf[2][2];
#pragma unroll
  for (int tt = 0; tt < 2; ++tt)
#pragma unroll
    for (int kk = 0; kk < 2; ++kk) {
      int trow = wid * 32 + tt * 16 + r;
      caf[tt][kk] = *(const bf16x8*)&Cs[trow * 64 + ((((kk * 4 + g)) ^ (trow & 7)) << 3)];
    }

  f32x4 accY[2][4], acc2[2][4];
#pragma unroll
  for (int tt = 0; tt < 2; ++tt)
#pragma unroll
    for (int pt = 0; pt < 4; ++pt) {
      accY[tt][pt] = (f32x4){0.f, 0.f, 0.f, 0.f};
      acc2[tt][pt] = (f32x4){0.f, 0.f, 0.f, 0.f};
    }
#pragma unroll
  for (int tt = 0; tt < 2; ++tt) {
    int trow = wid * 32 + tt * 16 + r;
#pragma unroll
    for (int kk = 0; kk < 4; ++kk) {
      if (kk <= wid) {
        int k0 = kk * 32 + g * 8;
        bf16x8 ga = *(const bf16x8*)&Gs[trow * 128 + (k0 ^ ((trow & 7) << 3))];
#pragma unroll
        for (int pt = 0; pt < 4; ++pt) {
          int prow = pt * 16 + r;
          bf16x8 xb = *(const bf16x8*)&Xt[prow * 128 + (k0 ^ ((prow & 7) << 3))];
          accY[tt][pt] = __builtin_amdgcn_mfma_f32_16x16x32_bf16(ga, xb, accY[tt][pt], 0, 0, 0);
        }
      }
    }
#pragma unroll
    for (int kk = 0; kk < 2; ++kk) {
#pragma unroll
      for (int pt = 0; pt < 4; ++pt) {
        int prow = pt * 16 + r;
        bf16x8 hb = *(const bf16x8*)&hts[prow * 64 + ((((kk * 4 + g)) ^ (prow & 7)) << 3)];
        acc2[tt][pt] = __builtin_amdgcn_mfma_f32_16x16x32_bf16(caf[tt][kk], hb, acc2[tt][pt], 0, 0, 0);
      }
    }
  }

  const float Dh = Dp[h];
#pragma unroll
  for (int tt = 0; tt < 2; ++tt) {
#pragma unroll
    for (int j = 0; j < 4; ++j) {
      int trow = wid * 32 + tt * 16 + g * 4 + j;
      float el = expf(Lat[trow]);
      size_t yrow = ((size_t)(b * LTT + (c - 8) * 128 + trow)) << 10;
#pragma unroll
      for (int pt = 0; pt < 4; ++pt) {
        int p = pt * 16 + r;
        float xv = (float)Xt[p * 128 + (trow ^ ((p & 7) << 3))];
        float yv = accY[tt][pt][j] + el * acc2[tt][pt][j] + Dh * xv;
        ybuf[yrow + h * 64 + p] = (bf16_t)yv;
      }
    }
  }
}

__global__ __launch_bounds__(256)
void gate_norm_k(const bf16_t* __restrict__ zbuf, const bf16_t* __restrict__ ybuf,
                 const float* __restrict__ norm_w, bf16_t* __restrict__ yn)
{
  __shared__ float sbuf[4];
  const int row = blockIdx.x;
  const int tid = threadIdx.x;
  bf16x4 yv = *(const bf16x4*)&ybuf[(size_t)row * DINNER + tid * 4];
  bf16x4 zv = *(const bf16x4*)&zbuf[(size_t)row * DINNER + tid * 4];
  float v[4];
#pragma unroll
  for (int c = 0; c < 4; ++c) {
    float y = (float)yv[c], z = (float)zv[c];
    v[c] = y * (z / (1.f + expf(-z)));
  }
  float ss = block_sum(v[0]*v[0] + v[1]*v[1] + v[2]*v[2] + v[3]*v[3], sbuf);
  float inv = rsqrtf(ss * (1.f / 1024.f) + 1e-5f);
  float4 nw = *(const float4*)&norm_w[tid * 4];
  bf16x4 o;
  o[0] = (bf16_t)(v[0] * inv * nw.x); o[1] = (bf16_t)(v[1] * inv * nw.y);
  o[2] = (bf16_t)(v[2] * inv * nw.z); o[3] = (bf16_t)(v[3] * inv * nw.w);
  *(bf16x4*)&yn[(size_t)row * DINNER + tid * 4] = o;
}

__global__ __launch_bounds__(256)
void rms_k(const float* __restrict__ in, bf16_t* __restrict__ out)
{
  __shared__ float sbuf[4];
  const int row = blockIdx.x;
  const int tid = threadIdx.x;
  float2 v = *(const float2*)&in[(size_t)row * DMODEL + tid * 2];
  float ss = block_sum(v.x * v.x + v.y * v.y, sbuf);
  float inv = rsqrtf(ss * (1.f / 512.f) + 1e-6f);
  bf16x2 o; o[0] = (bf16_t)(v.x * inv); o[1] = (bf16_t)(v.y * inv);
  *(bf16x2*)&out[(size_t)row * DMODEL + tid * 2] = o;
}

extern "C" void kernel_launch(void* const* d_in, const int* in_sizes, int n_in,
                              void* d_out, int out_size, void* d_ws, size_t ws_size,
                              hipStream_t stream)
{
  const float* tgt        = (const float*)d_in[0];
  const float* memory     = (const float*)d_in[1];
  const float* mem_mask   = (const float*)d_in[2];
  const float* tgt_mask   = (const float*)d_in[3];
  const float* in_proj_w  = (const float*)d_in[4];
  const float* conv_w     = (const float*)d_in[5];
  const float* conv_b     = (const float*)d_in[6];
  const float* dt_bias    = (const float*)d_in[7];
  const float* A_log      = (const float*)d_in[8];
  const float* Dp         = (const float*)d_in[9];
  const float* norm_w     = (const float*)d_in[10];
  const float* out_proj_w = (const float*)d_in[11];
  const float* fc1_w      = (const float*)d_in[12];
  const float* fc1_b      = (const float*)d_in[13];
  const float* fc2_w      = (const float*)d_in[14];
  const float* fc2_b      = (const float*)d_in[15];

  char* wsb = (char*)d_ws;
  bf16_t* u     = (bf16_t*)(wsb + 0);            // 25,165,824 B
  bf16_t* zbuf  = (bf16_t*)(wsb + 25165824);     // 16,777,216 B
  bf16_t* xbc   = (bf16_t*)(wsb + 41943040);     // 56,623,104 B
  float*  dts   = (float*)(wsb + 98566144);      // 1,572,864 B
  float*  labuf = (float*)(wsb + 100139008);     // 1,572,864 B
  float*  tgtm  = (float*)(wsb + 101711872);     // 16,777,216 B
  bf16_t* hend  = (bf16_t*)(wsb + 118489088);    // 25,165,824 B
  float*  Lacum = (float*)(wsb + 143667200);     // 1,572,864 B
  float*  Akb   = (float*)(wsb + 145240064);     // 12,288 B
  bf16_t* BtG   = (bf16_t*)(wsb + 145252352);    // 3,145,728 B
  bf16_t* Sg    = (bf16_t*)(wsb + 148398080);    // 2,097,152 B
  bf16_t* CcG   = (bf16_t*)(wsb + 150495232);    // 1,048,576 B
  bf16_t* wip   = (bf16_t*)(wsb + 160444416);    // weights (bf16, contiguous)
  bf16_t* wop   = wip + 1122304;
  bf16_t* wf1   = wop + 524288;
  bf16_t* wf2   = wf1 + 1048576;
  // overlays:
  bf16_t* ybuf  = (bf16_t*)(wsb + 0);            // over u (dead after in_proj)
  bf16_t* yn    = (bf16_t*)(wsb + 41943040);     // over xbc (dead after ssd_y)
  float*  tres  = (float*)(wsb + 58720256);      // over xbc+16M
  bf16_t* t1    = (bf16_t*)(wsb + 75497472);     // over xbc+32M
  bf16_t* hbuf  = (bf16_t*)(wsb + 0);            // over u+zbuf (dead after gate_norm)
  float* outp = (float*)d_out;

  cvt_all<<<3656, 256, 0, stream>>>(in_proj_w, out_proj_w, fc1_w, fc2_w, wip);
  prep_u<<<BB * LL, 256, 0, stream>>>(tgt, memory, mem_mask, tgt_mask, u, tgtm);
  gemm_big<4><<<dim3(18, 96), 512, 0, stream>>>(u, wip, BB * LL, DIPROJ, DMODEL,
      nullptr, nullptr, zbuf, xbc, dts, labuf, dt_bias, A_log);
  sbc_k<<<dim3(12, BB), 256, 0, stream>>>(xbc, conv_w, conv_b, BtG, Sg, CcG);
  ssd_hend<<<dim3(12, BB * NH), 256, 0, stream>>>(xbc, dts, labuf, conv_w, conv_b,
      BtG, hend, Lacum, Akb);
  ssd_y<<<dim3(4, BB * NH), 256, 0, stream>>>(xbc, dts, hend, Akb, Lacum, Sg, CcG,
      conv_w, conv_b, Dp, ybuf);
  gate_norm_k<<<BB * LTT, 256, 0, stream>>>(zbuf, ybuf, norm_w, yn);
  gemm_abf<3><<<dim3(4, 64), 256, 0, stream>>>(yn, wop, BB * LTT, DMODEL, DINNER,
      tres, nullptr, tgtm);
  rms_k<<<BB * LTT, 256, 0, stream>>>(tres, t1);
  gemm_big<1><<<dim3(16, 32), 512, 0, stream>>>(t1, wf1, BB * LTT, DFF2, DMODEL,
      hbuf, fc1_b, nullptr, nullptr, nullptr, nullptr, nullptr, nullptr);
  gemm_abf<2><<<dim3(4, 64), 256, 0, stream>>>(hbuf, wf2, BB * LTT, DMODEL, DFF2,
      outp, fc2_b, tres);
}